// Round 1
// baseline (1688.972 us; speedup 1.0000x reference)
//
#include <hip/hip_runtime.h>
#include <cstdint>
#include <cstddef>

#define N_NODES 50000
#define N_EDGES 1600000
#define IN_F 256
#define EDGE_F 64
#define HALF_F 128
#define BASE_F 384
#define OUT_F 256

// ---------------- CSR build ----------------

__global__ void hist_kernel(const int* __restrict__ src, const int* __restrict__ dst,
                            int* __restrict__ cnt_src, int* __restrict__ cnt_dst, int E) {
  int e = blockIdx.x * blockDim.x + threadIdx.x;
  if (e < E) {
    atomicAdd(&cnt_src[src[e]], 1);
    atomicAdd(&cnt_dst[dst[e]], 1);
  }
}

// single-block inclusive->exclusive scan (n up to ~64K fine)
__global__ void scan_kernel(const int* __restrict__ cnt, int* __restrict__ off,
                            int* __restrict__ cur, int n) {
  __shared__ int buf[2][1024];
  int carry = 0;
  for (int base = 0; base < n; base += 1024) {
    int i = base + (int)threadIdx.x;
    int v = (i < n) ? cnt[i] : 0;
    int pb = 0;
    buf[0][threadIdx.x] = v;
    __syncthreads();
    for (int ofs = 1; ofs < 1024; ofs <<= 1) {
      int val = buf[pb][threadIdx.x];
      if ((int)threadIdx.x >= ofs) val += buf[pb][threadIdx.x - ofs];
      buf[pb ^ 1][threadIdx.x] = val;
      pb ^= 1;
      __syncthreads();
    }
    int incl = buf[pb][threadIdx.x];
    if (i < n) { int ex = carry + incl - v; off[i] = ex; cur[i] = ex; }
    carry += buf[pb][1023];
    __syncthreads();
  }
  if (threadIdx.x == 0) off[n] = carry;
}

__global__ void dinv_kernel(const int* __restrict__ cnt_dst, float* __restrict__ dinv, int n) {
  int i = blockIdx.x * blockDim.x + threadIdx.x;
  if (i < n) dinv[i] = rsqrtf((float)cnt_dst[i] + 1.0f);
}

__global__ void fill_kernel(const int* __restrict__ src, const int* __restrict__ dst,
                            int* __restrict__ cur_src, int* __restrict__ cur_dst,
                            int* __restrict__ list_src, int* __restrict__ list_dst, int E) {
  int e = blockIdx.x * blockDim.x + threadIdx.x;
  if (e < E) {
    int s = src[e], d = dst[e];
    int p = atomicAdd(&cur_src[s], 1);
    list_src[p] = e;                 // edge id, to index edge_attr
    int q = atomicAdd(&cur_dst[d], 1);
    list_dst[q] = s;                 // src node id, to gather hw2
  }
}

// ---------------- edge-feature sum + projection + leaky_relu ----------------
// 4 waves/block, one wave per node; lane = feature (EDGE_F=64)
__global__ __launch_bounds__(256)
void edgefeat_kernel(const float* __restrict__ edge_attr,
                     const float* __restrict__ W_edge, const float* __restrict__ b_edge,
                     const int* __restrict__ off_src, const int* __restrict__ list_src,
                     float* __restrict__ proj, int n) {
  const int wave = threadIdx.x >> 6;
  const int lane = threadIdx.x & 63;
  const int node = blockIdx.x * 4 + wave;
  __shared__ float pn[4][64];

  float sum = 0.f;
  if (node < n) {
    int beg = off_src[node], end = off_src[node + 1];
    int idx = beg;
    for (; idx + 2 <= end; idx += 2) {
      int e0 = list_src[idx], e1 = list_src[idx + 1];
      sum += edge_attr[(size_t)e0 * EDGE_F + lane] + edge_attr[(size_t)e1 * EDGE_F + lane];
    }
    for (; idx < end; ++idx)
      sum += edge_attr[(size_t)list_src[idx] * EDGE_F + lane];
  }
  pn[wave][lane] = sum;
  __syncthreads();

  if (node < n) {
    float a0 = b_edge[lane];
    float a1 = b_edge[lane + 64];
    #pragma unroll 8
    for (int k = 0; k < EDGE_F; ++k) {
      float p = pn[wave][k];
      a0 += p * W_edge[k * HALF_F + lane];
      a1 += p * W_edge[k * HALF_F + lane + 64];
    }
    a0 = (a0 > 0.f) ? a0 : 0.01f * a0;
    a1 = (a1 > 0.f) ? a1 : 0.01f * a1;
    proj[(size_t)node * HALF_F + lane] = a0;
    proj[(size_t)node * HALF_F + lane + 64] = a1;
  }
}

// ---------------- fused GEMM: C[N,512] = [x|proj] @ [W_conv|W_res] ----------------
// cols 0..255 -> hw2 = dinv[row]*(h@W_conv); cols 256..511 -> hfin = h@W_res + b_conv + b_res
#define BM 128
#define BN 128
#define BK 16
#define LDA 132

__global__ __launch_bounds__(256)
void gemm_kernel(const float* __restrict__ x, const float* __restrict__ proj,
                 const float* __restrict__ Wc, const float* __restrict__ Wr,
                 const float* __restrict__ bconv, const float* __restrict__ bres,
                 const float* __restrict__ dinv,
                 float* __restrict__ hw2, float* __restrict__ hfin, int M) {
  __shared__ float As[BK * LDA];
  __shared__ float Bs[BK * BN];
  const int cb = blockIdx.y;                    // 0..3
  const float* __restrict__ B = (cb < 2) ? Wc : Wr;
  const int c0 = (cb & 1) * BN;                 // col offset within the 256-wide W
  const int row0 = blockIdx.x * BM;
  const int t = threadIdx.x;
  const int tx = t & 15, ty = t >> 4;

  float acc[8][8];
  #pragma unroll
  for (int i = 0; i < 8; ++i)
    #pragma unroll
    for (int j = 0; j < 8; ++j) acc[i][j] = 0.f;

  for (int kt = 0; kt < BASE_F / BK; ++kt) {
    const int k0 = kt * BK;
    __syncthreads();
    // stage A: 128 rows x 16 cols = 512 float4
    #pragma unroll
    for (int u = 0; u < 2; ++u) {
      int f = t + u * 256;
      int row = f >> 2, kq = f & 3;
      int rg = row0 + row;
      float4 av = make_float4(0.f, 0.f, 0.f, 0.f);
      if (rg < M) {
        if (k0 < IN_F) av = *(const float4*)(x + (size_t)rg * IN_F + k0 + kq * 4);
        else           av = *(const float4*)(proj + (size_t)rg * HALF_F + (k0 - IN_F) + kq * 4);
      }
      int kk0 = kq * 4;
      As[(kk0 + 0) * LDA + row] = av.x;
      As[(kk0 + 1) * LDA + row] = av.y;
      As[(kk0 + 2) * LDA + row] = av.z;
      As[(kk0 + 3) * LDA + row] = av.w;
    }
    // stage B: 16 rows x 128 cols = 512 float4
    #pragma unroll
    for (int u = 0; u < 2; ++u) {
      int f = t + u * 256;
      int kk = f >> 5, cq = f & 31;
      float4 bv = *(const float4*)(B + (size_t)(k0 + kk) * OUT_F + c0 + cq * 4);
      *(float4*)(&Bs[kk * BN + cq * 4]) = bv;
    }
    __syncthreads();
    #pragma unroll
    for (int kk = 0; kk < BK; ++kk) {
      float a[8], b[8];
      *(float4*)(a)     = *(const float4*)(&As[kk * LDA + ty * 8]);
      *(float4*)(a + 4) = *(const float4*)(&As[kk * LDA + ty * 8 + 4]);
      *(float4*)(b)     = *(const float4*)(&Bs[kk * BN + tx * 8]);
      *(float4*)(b + 4) = *(const float4*)(&Bs[kk * BN + tx * 8 + 4]);
      #pragma unroll
      for (int i = 0; i < 8; ++i)
        #pragma unroll
        for (int j = 0; j < 8; ++j)
          acc[i][j] += a[i] * b[j];
    }
  }

  #pragma unroll
  for (int i = 0; i < 8; ++i) {
    int rg = row0 + ty * 8 + i;
    if (rg < M) {
      if (cb < 2) {
        float dv = dinv[rg];
        #pragma unroll
        for (int j = 0; j < 8; ++j) {
          int cc = c0 + tx * 8 + j;
          hw2[(size_t)rg * OUT_F + cc] = dv * acc[i][j];
        }
      } else {
        #pragma unroll
        for (int j = 0; j < 8; ++j) {
          int cc = c0 + tx * 8 + j;
          hfin[(size_t)rg * OUT_F + cc] = acc[i][j] + bconv[cc] + bres[cc];
        }
      }
    }
  }
}

// ---------------- final aggregation: out = relu(dinv*(sum hw2[src] + hw2[self]) + hfin) ----------------
__global__ __launch_bounds__(256)
void agg_kernel(const float* __restrict__ hw2, const float* __restrict__ hfin,
                const float* __restrict__ dinv,
                const int* __restrict__ off_dst, const int* __restrict__ list_dst,
                float* __restrict__ out, int n) {
  int node = blockIdx.x;
  int f = threadIdx.x;
  int beg = off_dst[node], end = off_dst[node + 1];
  float acc = hw2[(size_t)node * OUT_F + f];   // self-loop term (pre-scaled by dinv[node])
  int idx = beg;
  for (; idx + 4 <= end; idx += 4) {
    int s0 = list_dst[idx], s1 = list_dst[idx + 1];
    int s2 = list_dst[idx + 2], s3 = list_dst[idx + 3];
    acc += hw2[(size_t)s0 * OUT_F + f];
    acc += hw2[(size_t)s1 * OUT_F + f];
    acc += hw2[(size_t)s2 * OUT_F + f];
    acc += hw2[(size_t)s3 * OUT_F + f];
  }
  for (; idx < end; ++idx)
    acc += hw2[(size_t)list_dst[idx] * OUT_F + f];
  float o = dinv[node] * acc + hfin[(size_t)node * OUT_F + f];
  out[(size_t)node * OUT_F + f] = fmaxf(o, 0.f);
}

// ---------------- launch ----------------

extern "C" void kernel_launch(void* const* d_in, const int* in_sizes, int n_in,
                              void* d_out, int out_size, void* d_ws, size_t ws_size,
                              hipStream_t stream) {
  const float* x         = (const float*)d_in[0];
  const int*   edge_idx  = (const int*)d_in[1];
  const float* edge_attr = (const float*)d_in[2];
  // d_in[3] = batch (unused by the reference output)
  const float* W_edge    = (const float*)d_in[4];
  const float* b_edge    = (const float*)d_in[5];
  const float* W_conv    = (const float*)d_in[6];
  const float* b_conv    = (const float*)d_in[7];
  const float* W_res     = (const float*)d_in[8];
  const float* b_res     = (const float*)d_in[9];
  float* out = (float*)d_out;

  const int N = N_NODES;
  const int E = N_EDGES;
  const int* src = edge_idx;
  const int* dst = edge_idx + E;

  // workspace carve-up (256B aligned)
  char* p = (char*)d_ws;
  auto alloc = [&](size_t bytes) -> void* {
    void* r = (void*)p;
    p += (bytes + 255) & ~(size_t)255;
    return r;
  };
  int*   cnt_src  = (int*)alloc((size_t)N * 4);
  int*   cnt_dst  = (int*)alloc((size_t)N * 4);
  int*   off_src  = (int*)alloc((size_t)(N + 1) * 4);
  int*   off_dst  = (int*)alloc((size_t)(N + 1) * 4);
  int*   cur_src  = (int*)alloc((size_t)N * 4);
  int*   cur_dst  = (int*)alloc((size_t)N * 4);
  float* dinv     = (float*)alloc((size_t)N * 4);
  int*   list_src = (int*)alloc((size_t)E * 4);
  int*   list_dst = (int*)alloc((size_t)E * 4);
  float* proj     = (float*)alloc((size_t)N * HALF_F * 4);
  float* hw2      = (float*)alloc((size_t)N * OUT_F * 4);
  float* hfin     = (float*)alloc((size_t)N * OUT_F * 4);
  (void)ws_size; (void)n_in; (void)in_sizes; (void)out_size;

  hipMemsetAsync(cnt_src, 0, (size_t)N * 4, stream);
  hipMemsetAsync(cnt_dst, 0, (size_t)N * 4, stream);

  const int eb = (E + 255) / 256;
  hist_kernel<<<eb, 256, 0, stream>>>(src, dst, cnt_src, cnt_dst, E);
  scan_kernel<<<1, 1024, 0, stream>>>(cnt_src, off_src, cur_src, N);
  scan_kernel<<<1, 1024, 0, stream>>>(cnt_dst, off_dst, cur_dst, N);
  dinv_kernel<<<(N + 255) / 256, 256, 0, stream>>>(cnt_dst, dinv, N);
  fill_kernel<<<eb, 256, 0, stream>>>(src, dst, cur_src, cur_dst, list_src, list_dst, E);

  edgefeat_kernel<<<(N + 3) / 4, 256, 0, stream>>>(edge_attr, W_edge, b_edge,
                                                   off_src, list_src, proj, N);

  dim3 ggrid((N + BM - 1) / BM, 4);
  gemm_kernel<<<ggrid, 256, 0, stream>>>(x, proj, W_conv, W_res, b_conv, b_res,
                                         dinv, hw2, hfin, N);

  agg_kernel<<<N, 256, 0, stream>>>(hw2, hfin, dinv, off_dst, list_dst, out, N);
}

// Round 4
// 1226.502 us; speedup vs baseline: 1.3771x; 1.3771x over previous
//
#include <hip/hip_runtime.h>
#include <cstdint>
#include <cstddef>

#define N_NODES 50000
#define N_EDGES 1600000
#define IN_F 256
#define EDGE_F 64
#define HALF_F 128
#define BASE_F 384
#define OUT_F 256
#define NB 196          // ceil(N_NODES / 256) buckets of 256 nodes
#define EPB 8192        // edges per bin block

// ---------------- bucket counting (LDS-aggregated) ----------------
__global__ __launch_bounds__(256)
void count_buckets(const int* __restrict__ src, const int* __restrict__ dst,
                   int* __restrict__ bcs, int* __restrict__ bcd, int E) {
  __shared__ int hs[NB], hd[NB];
  for (int i = threadIdx.x; i < NB; i += 256) { hs[i] = 0; hd[i] = 0; }
  __syncthreads();
  const int stride = gridDim.x * 256;
  for (int e = blockIdx.x * 256 + threadIdx.x; e < E; e += stride) {
    atomicAdd(&hs[src[e] >> 8], 1);
    atomicAdd(&hd[dst[e] >> 8], 1);
  }
  __syncthreads();
  for (int i = threadIdx.x; i < NB; i += 256) {
    if (hs[i]) atomicAdd(&bcs[i], hs[i]);
    if (hd[i]) atomicAdd(&bcd[i], hd[i]);
  }
}

// ---------------- tiny scan over 196 bucket counts (both arrays) ----------------
__global__ void bucket_scan(const int* __restrict__ bcs, const int* __restrict__ bcd,
                            int* __restrict__ bos, int* __restrict__ bod,
                            int* __restrict__ curs, int* __restrict__ curd) {
  __shared__ int b[2][256];
  const int t = threadIdx.x;
  for (int a = 0; a < 2; ++a) {
    const int* c = a ? bcd : bcs;
    int* off = a ? bod : bos;
    int* cur = a ? curd : curs;
    int v = (t < NB) ? c[t] : 0;
    b[0][t] = v;
    __syncthreads();
    int pb = 0;
    for (int o = 1; o < 256; o <<= 1) {
      int x = b[pb][t];
      if (t >= o) x += b[pb][t - o];
      b[pb ^ 1][t] = x;
      pb ^= 1;
      __syncthreads();
    }
    int incl = b[pb][t];
    int excl = incl - v;
    if (t < NB) { off[t] = excl; cur[t] = excl; }
    if (t == NB - 1) off[NB] = incl;
    __syncthreads();
  }
}

// ---------------- bin edges by bucket (block-aggregated cursors) ----------------
// bin_s[pos] = (e<<8)|(s&255)  grouped by s>>8 ;  bin_d[pos] = (s<<8)|(d&255) grouped by d>>8
__global__ __launch_bounds__(256)
void bin_kernel(const int* __restrict__ src, const int* __restrict__ dst,
                int* __restrict__ curs, int* __restrict__ curd,
                unsigned* __restrict__ bin_s, unsigned* __restrict__ bin_d, int E) {
  __shared__ int hs[NB], hd[NB];
  __shared__ int cs[NB], cd[NB];
  const int base = blockIdx.x * EPB;
  const int end = min(base + EPB, E);
  for (int i = threadIdx.x; i < NB; i += 256) { hs[i] = 0; hd[i] = 0; }
  __syncthreads();
  for (int e = base + threadIdx.x; e < end; e += 256) {
    atomicAdd(&hs[src[e] >> 8], 1);
    atomicAdd(&hd[dst[e] >> 8], 1);
  }
  __syncthreads();
  for (int i = threadIdx.x; i < NB; i += 256) {
    cs[i] = hs[i] ? atomicAdd(&curs[i], hs[i]) : 0;
    cd[i] = hd[i] ? atomicAdd(&curd[i], hd[i]) : 0;
  }
  __syncthreads();
  for (int e = base + threadIdx.x; e < end; e += 256) {
    int s = src[e], d = dst[e];
    int ps = atomicAdd(&cs[s >> 8], 1);
    bin_s[ps] = ((unsigned)e << 8) | (unsigned)(s & 255);
    int pd = atomicAdd(&cd[d >> 8], 1);
    bin_d[pd] = ((unsigned)s << 8) | (unsigned)(d & 255);
  }
}

// ---------------- per-bucket: node offsets + dinv + CSR scatter ----------------
// grid (NB, 2): y==0 -> src list (payload = edge id), y==1 -> dst list (payload = src node)
__global__ __launch_bounds__(256)
void scatter_kernel(const unsigned* __restrict__ bin_s, const unsigned* __restrict__ bin_d,
                    const int* __restrict__ bos, const int* __restrict__ bod,
                    int* __restrict__ off_s, int* __restrict__ off_d,
                    int* __restrict__ list_s, int* __restrict__ list_d,
                    float* __restrict__ dinv) {
  const int b = blockIdx.x;
  const int isDst = blockIdx.y;
  const unsigned* __restrict__ bin = isDst ? bin_d : bin_s;
  const int* __restrict__ boff = isDst ? bod : bos;
  int* __restrict__ off = isDst ? off_d : off_s;
  int* __restrict__ list = isDst ? list_d : list_s;

  __shared__ int cnt[256];
  __shared__ int sb[2][256];
  __shared__ int cur[256];
  const int t = threadIdx.x;
  cnt[t] = 0;
  __syncthreads();

  const int beg = boff[b], endp = boff[b + 1];
  for (int i = beg + t; i < endp; i += 256) atomicAdd(&cnt[bin[i] & 255u], 1);
  __syncthreads();

  // exclusive scan of cnt
  sb[0][t] = cnt[t];
  __syncthreads();
  int pb = 0;
  for (int o = 1; o < 256; o <<= 1) {
    int x = sb[pb][t];
    if (t >= o) x += sb[pb][t - o];
    sb[pb ^ 1][t] = x;
    pb ^= 1;
    __syncthreads();
  }
  const int excl = sb[pb][t] - cnt[t];

  const int node = b * 256 + t;
  if (node <= N_NODES) off[node] = beg + excl;   // covers off[N]=E at b=NB-1
  if (isDst && node < N_NODES) dinv[node] = rsqrtf((float)cnt[t] + 1.0f);
  cur[t] = beg + excl;
  __syncthreads();

  for (int i = beg + t; i < endp; i += 256) {
    unsigned v = bin[i];
    int p = atomicAdd(&cur[v & 255u], 1);
    list[p] = (int)(v >> 8);
  }
}

// ---------------- edge-feature sum + projection + leaky_relu ----------------
__global__ __launch_bounds__(256)
void edgefeat_kernel(const float* __restrict__ edge_attr,
                     const float* __restrict__ W_edge, const float* __restrict__ b_edge,
                     const int* __restrict__ off_src, const int* __restrict__ list_src,
                     float* __restrict__ proj, int n) {
  const int wave = threadIdx.x >> 6;
  const int lane = threadIdx.x & 63;
  const int node = blockIdx.x * 4 + wave;
  __shared__ float pn[4][64];

  float sum = 0.f;
  if (node < n) {
    int beg = off_src[node], end = off_src[node + 1];
    int idx = beg;
    for (; idx + 2 <= end; idx += 2) {
      int e0 = list_src[idx], e1 = list_src[idx + 1];
      sum += edge_attr[(size_t)e0 * EDGE_F + lane] + edge_attr[(size_t)e1 * EDGE_F + lane];
    }
    for (; idx < end; ++idx)
      sum += edge_attr[(size_t)list_src[idx] * EDGE_F + lane];
  }
  pn[wave][lane] = sum;
  __syncthreads();

  if (node < n) {
    float a0 = b_edge[lane];
    float a1 = b_edge[lane + 64];
    #pragma unroll 8
    for (int k = 0; k < EDGE_F; ++k) {
      float p = pn[wave][k];
      a0 += p * W_edge[k * HALF_F + lane];
      a1 += p * W_edge[k * HALF_F + lane + 64];
    }
    a0 = (a0 > 0.f) ? a0 : 0.01f * a0;
    a1 = (a1 > 0.f) ? a1 : 0.01f * a1;
    proj[(size_t)node * HALF_F + lane] = a0;
    proj[(size_t)node * HALF_F + lane + 64] = a1;
  }
}

// ---------------- fused GEMM: C[N,512] = [x|proj] @ [W_conv|W_res] ----------------
#define BM 128
#define BN 128
#define BK 16
#define LDA 132

__global__ __launch_bounds__(256)
void gemm_kernel(const float* __restrict__ x, const float* __restrict__ proj,
                 const float* __restrict__ Wc, const float* __restrict__ Wr,
                 const float* __restrict__ bconv, const float* __restrict__ bres,
                 const float* __restrict__ dinv,
                 float* __restrict__ hw2, float* __restrict__ hfin, int M) {
  __shared__ float As[BK * LDA];
  __shared__ float Bs[BK * BN];
  const int cb = blockIdx.y;                    // 0..3
  const float* __restrict__ B = (cb < 2) ? Wc : Wr;
  const int c0 = (cb & 1) * BN;
  const int row0 = blockIdx.x * BM;
  const int t = threadIdx.x;
  const int tx = t & 15, ty = t >> 4;

  float acc[8][8];
  #pragma unroll
  for (int i = 0; i < 8; ++i)
    #pragma unroll
    for (int j = 0; j < 8; ++j) acc[i][j] = 0.f;

  for (int kt = 0; kt < BASE_F / BK; ++kt) {
    const int k0 = kt * BK;
    __syncthreads();
    #pragma unroll
    for (int u = 0; u < 2; ++u) {
      int f = t + u * 256;
      int row = f >> 2, kq = f & 3;
      int rg = row0 + row;
      float4 av = make_float4(0.f, 0.f, 0.f, 0.f);
      if (rg < M) {
        if (k0 < IN_F) av = *(const float4*)(x + (size_t)rg * IN_F + k0 + kq * 4);
        else           av = *(const float4*)(proj + (size_t)rg * HALF_F + (k0 - IN_F) + kq * 4);
      }
      int kk0 = kq * 4;
      As[(kk0 + 0) * LDA + row] = av.x;
      As[(kk0 + 1) * LDA + row] = av.y;
      As[(kk0 + 2) * LDA + row] = av.z;
      As[(kk0 + 3) * LDA + row] = av.w;
    }
    #pragma unroll
    for (int u = 0; u < 2; ++u) {
      int f = t + u * 256;
      int kk = f >> 5, cq = f & 31;
      float4 bv = *(const float4*)(B + (size_t)(k0 + kk) * OUT_F + c0 + cq * 4);
      *(float4*)(&Bs[kk * BN + cq * 4]) = bv;
    }
    __syncthreads();
    #pragma unroll
    for (int kk = 0; kk < BK; ++kk) {
      float a[8], bb[8];
      *(float4*)(a)      = *(const float4*)(&As[kk * LDA + ty * 8]);
      *(float4*)(a + 4)  = *(const float4*)(&As[kk * LDA + ty * 8 + 4]);
      *(float4*)(bb)     = *(const float4*)(&Bs[kk * BN + tx * 8]);
      *(float4*)(bb + 4) = *(const float4*)(&Bs[kk * BN + tx * 8 + 4]);
      #pragma unroll
      for (int i = 0; i < 8; ++i)
        #pragma unroll
        for (int j = 0; j < 8; ++j)
          acc[i][j] += a[i] * bb[j];
    }
  }

  #pragma unroll
  for (int i = 0; i < 8; ++i) {
    int rg = row0 + ty * 8 + i;
    if (rg < M) {
      if (cb < 2) {
        float dv = dinv[rg];
        #pragma unroll
        for (int j = 0; j < 8; ++j) {
          int cc = c0 + tx * 8 + j;
          hw2[(size_t)rg * OUT_F + cc] = dv * acc[i][j];
        }
      } else {
        #pragma unroll
        for (int j = 0; j < 8; ++j) {
          int cc = c0 + tx * 8 + j;
          hfin[(size_t)rg * OUT_F + cc] = acc[i][j] + bconv[cc] + bres[cc];
        }
      }
    }
  }
}

// ---------------- final aggregation ----------------
__global__ __launch_bounds__(256)
void agg_kernel(const float* __restrict__ hw2, const float* __restrict__ hfin,
                const float* __restrict__ dinv,
                const int* __restrict__ off_dst, const int* __restrict__ list_dst,
                float* __restrict__ out, int n) {
  int node = blockIdx.x;
  int f = threadIdx.x;
  int beg = off_dst[node], end = off_dst[node + 1];
  float acc = hw2[(size_t)node * OUT_F + f];   // self-loop term (pre-scaled by dinv[node])
  int idx = beg;
  for (; idx + 4 <= end; idx += 4) {
    int s0 = list_dst[idx], s1 = list_dst[idx + 1];
    int s2 = list_dst[idx + 2], s3 = list_dst[idx + 3];
    acc += hw2[(size_t)s0 * OUT_F + f];
    acc += hw2[(size_t)s1 * OUT_F + f];
    acc += hw2[(size_t)s2 * OUT_F + f];
    acc += hw2[(size_t)s3 * OUT_F + f];
  }
  for (; idx < end; ++idx)
    acc += hw2[(size_t)list_dst[idx] * OUT_F + f];
  float o = dinv[node] * acc + hfin[(size_t)node * OUT_F + f];
  out[(size_t)node * OUT_F + f] = fmaxf(o, 0.f);
}

// ---------------- launch ----------------

extern "C" void kernel_launch(void* const* d_in, const int* in_sizes, int n_in,
                              void* d_out, int out_size, void* d_ws, size_t ws_size,
                              hipStream_t stream) {
  const float* x         = (const float*)d_in[0];
  const int*   edge_idx  = (const int*)d_in[1];
  const float* edge_attr = (const float*)d_in[2];
  const float* W_edge    = (const float*)d_in[4];
  const float* b_edge    = (const float*)d_in[5];
  const float* W_conv    = (const float*)d_in[6];
  const float* b_conv    = (const float*)d_in[7];
  const float* W_res     = (const float*)d_in[8];
  const float* b_res     = (const float*)d_in[9];
  float* out = (float*)d_out;

  const int N = N_NODES;
  const int E = N_EDGES;
  const int* src = edge_idx;
  const int* dst = edge_idx + E;

  char* p = (char*)d_ws;
  auto alloc = [&](size_t bytes) -> void* {
    void* r = (void*)p;
    p += (bytes + 255) & ~(size_t)255;
    return r;
  };
  int*      bcs    = (int*)alloc((size_t)NB * 4);
  int*      bcd    = (int*)alloc((size_t)NB * 4);
  int*      bos    = (int*)alloc((size_t)(NB + 1) * 4);
  int*      bod    = (int*)alloc((size_t)(NB + 1) * 4);
  int*      curs   = (int*)alloc((size_t)NB * 4);
  int*      curd   = (int*)alloc((size_t)NB * 4);
  int*      off_s  = (int*)alloc((size_t)(N + 1) * 4);
  int*      off_d  = (int*)alloc((size_t)(N + 1) * 4);
  float*    dinv   = (float*)alloc((size_t)N * 4);
  unsigned* bin_s  = (unsigned*)alloc((size_t)E * 4);
  unsigned* bin_d  = (unsigned*)alloc((size_t)E * 4);
  int*      list_s = (int*)alloc((size_t)E * 4);
  int*      list_d = (int*)alloc((size_t)E * 4);
  float*    proj   = (float*)alloc((size_t)N * HALF_F * 4);
  float*    hw2    = (float*)alloc((size_t)N * OUT_F * 4);
  float*    hfin   = out;   // gemm writes residual part to d_out; agg reads-then-overwrites elementwise
  (void)ws_size; (void)n_in; (void)in_sizes; (void)out_size;

  hipMemsetAsync(bcs, 0, (size_t)NB * 4, stream);
  hipMemsetAsync(bcd, 0, (size_t)NB * 4, stream);

  count_buckets<<<256, 256, 0, stream>>>(src, dst, bcs, bcd, E);
  bucket_scan<<<1, 256, 0, stream>>>(bcs, bcd, bos, bod, curs, curd);
  bin_kernel<<<(E + EPB - 1) / EPB, 256, 0, stream>>>(src, dst, curs, curd, bin_s, bin_d, E);
  scatter_kernel<<<dim3(NB, 2), 256, 0, stream>>>(bin_s, bin_d, bos, bod,
                                                  off_s, off_d, list_s, list_d, dinv);

  edgefeat_kernel<<<(N + 3) / 4, 256, 0, stream>>>(edge_attr, W_edge, b_edge,
                                                   off_s, list_s, proj, N);

  dim3 ggrid((N + BM - 1) / BM, 4);
  gemm_kernel<<<ggrid, 256, 0, stream>>>(x, proj, W_conv, W_res, b_conv, b_res,
                                         dinv, hw2, hfin, N);

  agg_kernel<<<N, 256, 0, stream>>>(hw2, hfin, dinv, off_d, list_d, out, N);
}